// Round 2
// baseline (193.134 us; speedup 1.0000x reference)
//
#include <hip/hip_runtime.h>
#include <hip/hip_bf16.h>

// KascadeReuseAttention  B=1, S=2048, DM=1024, H=16, D=64, T=16, NA=3
// Round-18 (base r17 = 151.9us): single change — attn DS-pipe diet.
// Theory: ~76 DS ops/wave (ts/qs/ws LDS traffic + bpermute shfls) saturate
// the per-CU DS unit (~24us of the ~37us attn time). Changes:
//   - ts LDS eliminated: 4 tile ids loaded once as wave-uniform broadcast
//     loads; token indices recomputed in VALU everywhere.
//   - qs LDS eliminated: q fragment read directly from global (2x uint4
//     broadcast loads of the wave's single 128B q row).
//   - quad reductions (xor1/xor2) via DPP quad_perm (VALU) instead of
//     ds_bpermute: phase-2 partials, softmax tail, phase-4 final reduce
//     (phase-4 lanes remapped tq=lane&3, dd=lane>>2 so the cross-token
//     reduce is intra-quad; same butterfly tree -> bit-identical).
//   - softmax weights: permuted store ww[(L&3)*16+(L>>2)] = w[L]; phase 4
//     reads its 16 weights as 4x ds_read_b128 instead of 16 scalar reads.
// DS ops/wave ~76 -> ~18. All else frozen: prep (r8), qkv 64x128 GLL
// 768-block (r15), gemm_out 64x64/512-block (r16).
// Known budget: ~45us harness ws-poison fill (immovable) + attn + ~25 qkv
// + ~10 prep + out + gaps.

#define S_LEN 2048
#define DM 1024
#define NH 16
#define HD 64

typedef __bf16 bf16x8 __attribute__((ext_vector_type(8)));
typedef float f32x4 __attribute__((ext_vector_type(4)));

static __device__ __forceinline__ unsigned short f2bf(float f) {
    union { float f; unsigned int i; } un;
    un.f = f;
    unsigned int r = un.i + 0x7FFFu + ((un.i >> 16) & 1u);  // RNE
    return (unsigned short)(r >> 16);
}
static __device__ __forceinline__ float bfu2f(unsigned short u) {
    union { unsigned int i; float f; } un;
    un.i = ((unsigned int)u) << 16;
    return un.f;
}
static __device__ __forceinline__ float bflo(unsigned int u) {
    union { unsigned int i; float f; } un;
    un.i = u << 16;
    return un.f;
}
static __device__ __forceinline__ float bfhi(unsigned int u) {
    union { unsigned int i; float f; } un;
    un.i = u & 0xFFFF0000u;
    return un.f;
}

// DPP quad_perm helper: returns x permuted within each 4-lane quad (VALU,
// no DS). CTRL: 0xB1 = [1,0,3,2] (xor1), 0x4E = [2,3,0,1] (xor2).
template <int CTRL>
static __device__ __forceinline__ float qperm(float x) {
    return __int_as_float(__builtin_amdgcn_update_dpp(
        0, __float_as_int(x), CTRL, 0xF, 0xF, true));
}

// async global->LDS, 16 B per lane; LDS dest = uniform base + lane*16.
static __device__ __forceinline__ void gll16(const unsigned short* g,
                                             unsigned short* l) {
    __builtin_amdgcn_global_load_lds(
        (const __attribute__((address_space(1))) unsigned int*)(uintptr_t)g,
        (__attribute__((address_space(3))) unsigned int*)(uintptr_t)l,
        16, 0, 0);
}

// ---------------------------------------------------------------------------
// prep: blocks [0,4096) transpose W* fp32->bf16 [n][k]; blocks [4096,5120)
// convert x fp32->bf16.
// ---------------------------------------------------------------------------
__global__ __launch_bounds__(256) void prep(
    const float* __restrict__ x, unsigned short* __restrict__ xb,
    const float* __restrict__ W0, const float* __restrict__ W1,
    const float* __restrict__ W2, const float* __restrict__ W3,
    unsigned short* __restrict__ T0, unsigned short* __restrict__ T1,
    unsigned short* __restrict__ T2, unsigned short* __restrict__ T3) {
    const int bx = blockIdx.x;
    if (bx < 4096) {
        const int z = bx >> 10, rem = bx & 1023;
        const float* W = (z == 0) ? W0 : (z == 1) ? W1 : (z == 2) ? W2 : W3;
        unsigned short* T = (z == 0) ? T0 : (z == 1) ? T1 : (z == 2) ? T2 : T3;
        __shared__ float t[32][33];
        const int bn = (rem & 31) * 32, bk = (rem >> 5) * 32;
        const int tx = threadIdx.x & 31, ty = threadIdx.x >> 5;
        #pragma unroll
        for (int m = 0; m < 4; ++m)
            t[ty + m * 8][tx] = W[(size_t)(bk + ty + m * 8) * 1024 + bn + tx];
        __syncthreads();
        #pragma unroll
        for (int m = 0; m < 4; ++m)
            T[(size_t)(bn + ty + m * 8) * 1024 + bk + tx] = f2bf(t[tx][ty + m * 8]);
    } else {
        const int i = (bx - 4096) * 2048 + threadIdx.x * 8;
        float4 f0 = *(const float4*)(x + i);
        float4 f1 = *(const float4*)(x + i + 4);
        ushort4 o0, o1;
        o0.x = f2bf(f0.x); o0.y = f2bf(f0.y); o0.z = f2bf(f0.z); o0.w = f2bf(f0.w);
        o1.x = f2bf(f1.x); o1.y = f2bf(f1.y); o1.z = f2bf(f1.z); o1.w = f2bf(f1.w);
        *(ushort4*)(xb + i) = o0;
        *(ushort4*)(xb + i + 4) = o1;
    }
}

// ---------------------------------------------------------------------------
// QKV GEMM (r15-verbatim): 64x128 tile, BK=32, grid (24,32) = 768 blocks
// (3/CU, no tail), global_load_lds width-16 staging. Fused RoPE epilogue,
// head-major bf16 out [H][S][64].
// ---------------------------------------------------------------------------
__global__ __launch_bounds__(256) void gemm_qkv(
    const unsigned short* __restrict__ xb,
    const unsigned short* __restrict__ Wtq, const unsigned short* __restrict__ Wtk,
    const unsigned short* __restrict__ Wtv,
    unsigned short* __restrict__ qh, unsigned short* __restrict__ kh,
    unsigned short* __restrict__ vh,
    const float* __restrict__ cs, const float* __restrict__ sn) {
    __shared__ __align__(16) unsigned short Al[64 * 32];
    __shared__ __align__(16) unsigned short Bl[128 * 32];
    const int tid = threadIdx.x;
    const int nb = blockIdx.x >> 3;
    const unsigned short* __restrict__ Bt = (nb == 0) ? Wtq : (nb == 1) ? Wtk : Wtv;
    unsigned short* __restrict__ OUT = (nb == 0) ? qh : (nb == 1) ? kh : vh;
    const int col0 = (blockIdx.x & 7) * 128;
    const int row0 = blockIdx.y * 64;
    const int lane = tid & 63, wvi = tid >> 6;
    const int wr = (wvi >> 1) * 32, wc = (wvi & 1) * 64;
    const int l15 = lane & 15, quad = lane >> 4;

    const int grow = lane >> 2;            // 0..15
    const int gkc = (lane & 3) * 8;        // element offset within row
    const unsigned short* gA = xb + (size_t)(row0 + wvi * 16 + grow) * 1024 + gkc;
    const unsigned short* gB = Bt + (size_t)(col0 + wvi * 32 + grow) * 1024 + gkc;
    unsigned short* lA = Al + (wvi * 16) * 32;   // wave-uniform LDS base
    unsigned short* lB = Bl + (wvi * 32) * 32;

    f32x4 acc[2][4] = {};
    for (int k0 = 0; k0 < 1024; k0 += 32) {
        __syncthreads();  // prior iter's ds_reads complete before overwrite
        gll16(gA + k0, lA);                       // A: 64 rows total
        gll16(gB + k0, lB);                       // B: 128 rows total
        gll16(gB + 16 * 1024 + k0, lB + 16 * 32);
        __syncthreads();  // drains vmcnt(0): GLL data landed
        bf16x8 af[2], bfr[4];
        #pragma unroll
        for (int i = 0; i < 2; ++i)
            af[i] = *(const bf16x8*)&Al[(wr + i * 16 + l15) * 32 + quad * 8];
        #pragma unroll
        for (int j = 0; j < 4; ++j)
            bfr[j] = *(const bf16x8*)&Bl[(wc + j * 16 + l15) * 32 + quad * 8];
        #pragma unroll
        for (int i = 0; i < 2; ++i)
            #pragma unroll
            for (int j = 0; j < 4; ++j)
                acc[i][j] = __builtin_amdgcn_mfma_f32_16x16x32_bf16(
                    af[i], bfr[j], acc[i][j], 0, 0, 0);
    }

    // epilogue: wave's 64 cols = one head; fused RoPE; head-major store
    const int hh = ((blockIdx.x & 7) << 1) + (wc >> 6);
    const bool dorope = (nb != 2);
    #pragma unroll
    for (int i = 0; i < 2; ++i) {
        const int rowb = row0 + wr + i * 16 + quad * 4;
        #pragma unroll
        for (int r = 0; r < 4; ++r) {
            const int s = rowb + r;
            float v0 = acc[i][0][r], v1 = acc[i][1][r];
            float v2 = acc[i][2][r], v3 = acc[i][3][r];
            if (dorope) {
                float c0 = cs[s * 32 + l15],      s0 = sn[s * 32 + l15];
                float c1 = cs[s * 32 + 16 + l15], s1 = sn[s * 32 + 16 + l15];
                float lo0 = v0 * c0 - v2 * s0;
                float hi0 = v2 * c0 + v0 * s0;
                float lo1 = v1 * c1 - v3 * s1;
                float hi1 = v3 * c1 + v1 * s1;
                v0 = lo0; v1 = lo1; v2 = hi0; v3 = hi1;
            }
            unsigned short* op = OUT + (size_t)hh * (S_LEN * 64) + (size_t)s * 64 + l15;
            op[0]  = f2bf(v0);
            op[16] = f2bf(v1);
            op[32] = f2bf(v2);
            op[48] = f2bf(v3);
        }
    }
}

// ---------------------------------------------------------------------------
// Attention (r18): one wave per (h,q). DS-pipe diet — no ts/qs LDS; tile
// ids held as wave-uniform values; quad reductions via DPP quad_perm;
// weights distributed via permuted store + 4x ds_read_b128.
// ---------------------------------------------------------------------------
__global__ __launch_bounds__(256) void attn_kernel(
    const unsigned short* __restrict__ qh, const unsigned short* __restrict__ kh,
    const unsigned short* __restrict__ vh, const int* __restrict__ anc,
    unsigned short* __restrict__ att) {
    __shared__ __align__(16) float ws[4][64];   // logits, token-indexed
    __shared__ __align__(16) float ww[4][64];   // weights, permuted layout
    const int w4 = threadIdx.x >> 6;
    const int lane = threadIdx.x & 63;
    const int wid = (blockIdx.x << 2) + w4;
    const int h = wid >> 11;
    const int qi = wid & 2047;
    const size_t hb = (size_t)h * (S_LEN * 64);

    // 4 tile ids, wave-uniform (broadcast loads; local tile computed)
    const size_t ab = ((size_t)h * S_LEN + qi) * 3;
    const int t0 = anc[ab];
    const int t1 = anc[ab + 1];
    const int t2 = anc[ab + 2];
    const int t3 = qi >> 4;

    const int c = lane & 3;
    const int t = lane >> 2;

    // q fragment direct from global: wave reads its single 128B q row
    // (4 distinct 32B segments, broadcast within 16-lane c-groups).
    const unsigned short* qp = qh + hb + (size_t)qi * 64 + c * 16;
    const uint4 q0 = *(const uint4*)qp;
    const uint4 q1 = *(const uint4*)(qp + 8);
    float qv[16];
    qv[0]  = bflo(q0.x); qv[1]  = bfhi(q0.x);
    qv[2]  = bflo(q0.y); qv[3]  = bfhi(q0.y);
    qv[4]  = bflo(q0.z); qv[5]  = bfhi(q0.z);
    qv[6]  = bflo(q0.w); qv[7]  = bfhi(q0.w);
    qv[8]  = bflo(q1.x); qv[9]  = bfhi(q1.x);
    qv[10] = bflo(q1.y); qv[11] = bfhi(q1.y);
    qv[12] = bflo(q1.z); qv[13] = bfhi(q1.z);
    qv[14] = bflo(q1.w); qv[15] = bfhi(q1.w);

    // phase 2: QK^T partial dots; lane (c,t) covers dims c*16.. of token t
    #pragma unroll
    for (int p = 0; p < 4; ++p) {
        const int tile = (p == 0) ? t0 : (p == 1) ? t1 : (p == 2) ? t2 : t3;
        const int tk = tile * 16 + t;
        const unsigned short* kp = kh + hb + (size_t)tk * 64 + c * 16;
        const uint4 k0 = *(const uint4*)kp;
        const uint4 k1 = *(const uint4*)(kp + 8);
        float part;
        part = bflo(k0.x) * qv[0];
        part = fmaf(bfhi(k0.x), qv[1], part);
        part = fmaf(bflo(k0.y), qv[2], part);
        part = fmaf(bfhi(k0.y), qv[3], part);
        part = fmaf(bflo(k0.z), qv[4], part);
        part = fmaf(bfhi(k0.z), qv[5], part);
        part = fmaf(bflo(k0.w), qv[6], part);
        part = fmaf(bfhi(k0.w), qv[7], part);
        part = fmaf(bflo(k1.x), qv[8], part);
        part = fmaf(bfhi(k1.x), qv[9], part);
        part = fmaf(bflo(k1.y), qv[10], part);
        part = fmaf(bfhi(k1.y), qv[11], part);
        part = fmaf(bflo(k1.z), qv[12], part);
        part = fmaf(bfhi(k1.z), qv[13], part);
        part = fmaf(bflo(k1.w), qv[14], part);
        part = fmaf(bfhi(k1.w), qv[15], part);
        // quad butterfly (xor1, xor2) via DPP — all 4 lanes get the sum
        part += qperm<0xB1>(part);
        part += qperm<0x4E>(part);
        if (c == 0) ws[w4][p * 16 + t] = part;
    }

    float logit = ws[w4][lane];
    const int slot = lane >> 4;
    const int tile_own = (slot == 0) ? t0 : (slot == 1) ? t1
                       : (slot == 2) ? t2 : t3;
    const int tok_own = tile_own * 16 + (lane & 15);
    const bool fut = tok_own > qi;
    logit = fut ? -1e30f : logit * 0.125f;

    float m = logit;
    m = fmaxf(m, __shfl_xor(m, 32, 64));
    m = fmaxf(m, __shfl_xor(m, 16, 64));
    m = fmaxf(m, __shfl_xor(m, 8, 64));
    m = fmaxf(m, __shfl_xor(m, 4, 64));
    m = fmaxf(m, qperm<0x4E>(m));   // xor2
    m = fmaxf(m, qperm<0xB1>(m));   // xor1
    const float e = fut ? 0.f : __expf(logit - m);
    float ssum = e;
    ssum += __shfl_xor(ssum, 32, 64);
    ssum += __shfl_xor(ssum, 16, 64);
    ssum += __shfl_xor(ssum, 8, 64);
    ssum += __shfl_xor(ssum, 4, 64);
    ssum += qperm<0x4E>(ssum);
    ssum += qperm<0xB1>(ssum);
    // permuted store: token L's weight -> ww[(L&3)*16 + (L>>2)]
    ww[w4][(lane & 3) * 16 + (lane >> 2)] = e / ssum;

    // phase 4: weighted V sum. lane = (tq = lane&3, dd = lane>>2); round r
    // covers token kk = r*4+tq; cross-token reduce is intra-quad (DPP).
    const int tq = lane & 3;
    const int dd = lane >> 2;
    const unsigned short* vbase = vh + hb + dd * 4;
    f32x4 wv[4];
    #pragma unroll
    for (int r4 = 0; r4 < 4; ++r4)
        wv[r4] = *(const f32x4*)&ww[w4][tq * 16 + r4 * 4];
    float a0 = 0.f, a1 = 0.f, a2 = 0.f, a3 = 0.f;
    #pragma unroll
    for (int r = 0; r < 16; ++r) {
        const int tile = (r < 4) ? t0 : (r < 8) ? t1 : (r < 12) ? t2 : t3;
        const int tok = tile * 16 + (r & 3) * 4 + tq;
        const uint2 vv = *(const uint2*)(vbase + (size_t)tok * 64);
        const float w = wv[r >> 2][r & 3];
        a0 = fmaf(w, bflo(vv.x), a0);
        a1 = fmaf(w, bfhi(vv.x), a1);
        a2 = fmaf(w, bflo(vv.y), a2);
        a3 = fmaf(w, bfhi(vv.y), a3);
    }
    // quad reduce (xor1, xor2) via DPP — same tree as r17's xor16/xor32
    a0 += qperm<0xB1>(a0); a0 += qperm<0x4E>(a0);
    a1 += qperm<0xB1>(a1); a1 += qperm<0x4E>(a1);
    a2 += qperm<0xB1>(a2); a2 += qperm<0x4E>(a2);
    a3 += qperm<0xB1>(a3); a3 += qperm<0x4E>(a3);
    if (tq == 0) {
        ushort4 o;
        o.x = f2bf(a0); o.y = f2bf(a1); o.z = f2bf(a2); o.w = f2bf(a3);
        *(ushort4*)&att[(size_t)qi * DM + h * HD + dd * 4] = o;
    }
}

// ---------------------------------------------------------------------------
// Out GEMM (r16-verbatim): 64x64 tile, grid (16,32) = 512 blocks = 2/CU.
// Wave tile 32x32; 2 GLL + 4 MFMA per wave per K-iter.
// ---------------------------------------------------------------------------
__global__ __launch_bounds__(256) void gemm_out(
    const unsigned short* __restrict__ A, const unsigned short* __restrict__ Bt,
    float* __restrict__ C) {
    __shared__ __align__(16) unsigned short Al[64 * 32];
    __shared__ __align__(16) unsigned short Bl[64 * 32];
    const int tid = threadIdx.x;
    const int col0 = blockIdx.x * 64;
    const int row0 = blockIdx.y * 64;
    const int lane = tid & 63, wvi = tid >> 6;
    const int wr = (wvi >> 1) * 32, wc = (wvi & 1) * 32;
    const int l15 = lane & 15, quad = lane >> 4;

    const int grow = lane >> 2;
    const int gkc = (lane & 3) * 8;
    const unsigned short* gA = A + (size_t)(row0 + wvi * 16 + grow) * 1024 + gkc;
    const unsigned short* gB = Bt + (size_t)(col0 + wvi * 16 + grow) * 1024 + gkc;
    unsigned short* lA = Al + (wvi * 16) * 32;   // wave-uniform
    unsigned short* lB = Bl + (wvi * 16) * 32;

    f32x4 acc[2][2] = {};
    for (int k0 = 0; k0 < 1024; k0 += 32) {
        __syncthreads();
        gll16(gA + k0, lA);                       // A: 64 rows total
        gll16(gB + k0, lB);                       // B: 64 rows total
        __syncthreads();
        bf16x8 af[2], bfr[2];
        #pragma unroll
        for (int i = 0; i < 2; ++i)
            af[i] = *(const bf16x8*)&Al[(wr + i * 16 + l15) * 32 + quad * 8];
        #pragma unroll
        for (int j = 0; j < 2; ++j)
            bfr[j] = *(const bf16x8*)&Bl[(wc + j * 16 + l15) * 32 + quad * 8];
        #pragma unroll
        for (int i = 0; i < 2; ++i)
            #pragma unroll
            for (int j = 0; j < 2; ++j)
                acc[i][j] = __builtin_amdgcn_mfma_f32_16x16x32_bf16(
                    af[i], bfr[j], acc[i][j], 0, 0, 0);
    }
    #pragma unroll
    for (int i = 0; i < 2; ++i) {
        const int rowb = row0 + wr + i * 16 + quad * 4;
        #pragma unroll
        for (int r = 0; r < 4; ++r) {
            float* crow = C + (size_t)(rowb + r) * 1024 + col0 + wc;
            #pragma unroll
            for (int j = 0; j < 2; ++j)
                crow[j * 16 + l15] = acc[i][j][r];
        }
    }
}

// ---------------------------------------------------------------------------
extern "C" void kernel_launch(void* const* d_in, const int* in_sizes, int n_in,
                              void* d_out, int out_size, void* d_ws, size_t ws_size,
                              hipStream_t stream) {
    const float* x   = (const float*)d_in[0];
    const float* Wq  = (const float*)d_in[1];
    const float* Wk  = (const float*)d_in[2];
    const float* Wv  = (const float*)d_in[3];
    const float* Wo  = (const float*)d_in[4];
    const float* cs  = (const float*)d_in[5];
    const float* sn  = (const float*)d_in[6];
    const int*   anc = (const int*)d_in[7];
    float* out = (float*)d_out;

    unsigned short* xb  = (unsigned short*)d_ws;
    unsigned short* Wtq = xb  + (size_t)2048 * 1024;
    unsigned short* Wtk = Wtq + (size_t)1024 * 1024;
    unsigned short* Wtv = Wtk + (size_t)1024 * 1024;
    unsigned short* Wto = Wtv + (size_t)1024 * 1024;
    unsigned short* qh  = Wto + (size_t)1024 * 1024;   // [H][S][64]
    unsigned short* kh  = qh  + (size_t)2048 * 1024;
    unsigned short* vh  = kh  + (size_t)2048 * 1024;
    unsigned short* att = vh  + (size_t)2048 * 1024;   // [S][H*D]

    prep<<<5120, 256, 0, stream>>>(x, xb, Wq, Wk, Wv, Wo, Wtq, Wtk, Wtv, Wto);
    gemm_qkv<<<dim3(24, 32), 256, 0, stream>>>(xb, Wtq, Wtk, Wtv,
                                               qh, kh, vh, cs, sn);
    attn_kernel<<<(S_LEN * NH) / 4, 256, 0, stream>>>(qh, kh, vh, anc, att);
    gemm_out<<<dim3(16, 32), 256, 0, stream>>>(att, Wto, out);
}

// Round 4
// 150.612 us; speedup vs baseline: 1.2823x; 1.2823x over previous
//
#include <hip/hip_runtime.h>
#include <hip/hip_bf16.h>

// KascadeReuseAttention  B=1, S=2048, DM=1024, H=16, D=64, T=16, NA=3
// Round-20 = r19 resubmitted verbatim (previous bench was an infra
// failure: "MI355X container failed twice" — no signal).
// r18 (attn DS-diet) REGRESSED to 193us: VGPR dropped to 40 -> compiler
// stopped hoisting K/V loads, exposing L2 latency serially (VALUBusy 30%,
// hbm 533 GB/s, nothing busy). Lesson: attn is latency-bound and lives on
// ILP; LDS round-trips + named scalars force liveness that keeps loads
// hoisted. attn reverted to r17 verbatim.
// Single change vs r17: gemm_qkv 2-phase LDS double-buffer (T3-min):
// stage tile t+1 into buf^1 before computing tile t, ONE barrier per
// K-step (drain after compute) instead of sync;GLL;sync with the vmcnt(0)
// drain fully exposed. LDS 12->24KB, still 3 blocks/CU. gemm_out frozen
// as control.
// Known budget: ~45us harness ws-poison fill (immovable) + ~35 attn +
// ~25 qkv + ~10 prep + out + gaps.

#define S_LEN 2048
#define DM 1024
#define NH 16
#define HD 64

typedef __bf16 bf16x8 __attribute__((ext_vector_type(8)));
typedef float f32x4 __attribute__((ext_vector_type(4)));

static __device__ __forceinline__ unsigned short f2bf(float f) {
    union { float f; unsigned int i; } un;
    un.f = f;
    unsigned int r = un.i + 0x7FFFu + ((un.i >> 16) & 1u);  // RNE
    return (unsigned short)(r >> 16);
}
static __device__ __forceinline__ float bfu2f(unsigned short u) {
    union { unsigned int i; float f; } un;
    un.i = ((unsigned int)u) << 16;
    return un.f;
}
static __device__ __forceinline__ float bflo(unsigned int u) {
    union { unsigned int i; float f; } un;
    un.i = u << 16;
    return un.f;
}
static __device__ __forceinline__ float bfhi(unsigned int u) {
    union { unsigned int i; float f; } un;
    un.i = u & 0xFFFF0000u;
    return un.f;
}

// async global->LDS, 16 B per lane; LDS dest = uniform base + lane*16.
static __device__ __forceinline__ void gll16(const unsigned short* g,
                                             unsigned short* l) {
    __builtin_amdgcn_global_load_lds(
        (const __attribute__((address_space(1))) unsigned int*)(uintptr_t)g,
        (__attribute__((address_space(3))) unsigned int*)(uintptr_t)l,
        16, 0, 0);
}

// ---------------------------------------------------------------------------
// prep: blocks [0,4096) transpose W* fp32->bf16 [n][k]; blocks [4096,5120)
// convert x fp32->bf16.
// ---------------------------------------------------------------------------
__global__ __launch_bounds__(256) void prep(
    const float* __restrict__ x, unsigned short* __restrict__ xb,
    const float* __restrict__ W0, const float* __restrict__ W1,
    const float* __restrict__ W2, const float* __restrict__ W3,
    unsigned short* __restrict__ T0, unsigned short* __restrict__ T1,
    unsigned short* __restrict__ T2, unsigned short* __restrict__ T3) {
    const int bx = blockIdx.x;
    if (bx < 4096) {
        const int z = bx >> 10, rem = bx & 1023;
        const float* W = (z == 0) ? W0 : (z == 1) ? W1 : (z == 2) ? W2 : W3;
        unsigned short* T = (z == 0) ? T0 : (z == 1) ? T1 : (z == 2) ? T2 : T3;
        __shared__ float t[32][33];
        const int bn = (rem & 31) * 32, bk = (rem >> 5) * 32;
        const int tx = threadIdx.x & 31, ty = threadIdx.x >> 5;
        #pragma unroll
        for (int m = 0; m < 4; ++m)
            t[ty + m * 8][tx] = W[(size_t)(bk + ty + m * 8) * 1024 + bn + tx];
        __syncthreads();
        #pragma unroll
        for (int m = 0; m < 4; ++m)
            T[(size_t)(bn + ty + m * 8) * 1024 + bk + tx] = f2bf(t[tx][ty + m * 8]);
    } else {
        const int i = (bx - 4096) * 2048 + threadIdx.x * 8;
        float4 f0 = *(const float4*)(x + i);
        float4 f1 = *(const float4*)(x + i + 4);
        ushort4 o0, o1;
        o0.x = f2bf(f0.x); o0.y = f2bf(f0.y); o0.z = f2bf(f0.z); o0.w = f2bf(f0.w);
        o1.x = f2bf(f1.x); o1.y = f2bf(f1.y); o1.z = f2bf(f1.z); o1.w = f2bf(f1.w);
        *(ushort4*)(xb + i) = o0;
        *(ushort4*)(xb + i + 4) = o1;
    }
}

// ---------------------------------------------------------------------------
// QKV GEMM (r19): 64x128 tile, BK=32, grid (24,32) = 768 blocks (3/CU),
// global_load_lds width-16 staging, 2-phase double-buffered: stage tile
// t+1 into buf^1 before computing tile t; one barrier per K-step.
// Fused RoPE epilogue, head-major bf16 out [H][S][64].
// ---------------------------------------------------------------------------
__global__ __launch_bounds__(256) void gemm_qkv(
    const unsigned short* __restrict__ xb,
    const unsigned short* __restrict__ Wtq, const unsigned short* __restrict__ Wtk,
    const unsigned short* __restrict__ Wtv,
    unsigned short* __restrict__ qh, unsigned short* __restrict__ kh,
    unsigned short* __restrict__ vh,
    const float* __restrict__ cs, const float* __restrict__ sn) {
    __shared__ __align__(16) unsigned short Al[2][64 * 32];
    __shared__ __align__(16) unsigned short Bl[2][128 * 32];
    const int tid = threadIdx.x;
    const int nb = blockIdx.x >> 3;
    const unsigned short* __restrict__ Bt = (nb == 0) ? Wtq : (nb == 1) ? Wtk : Wtv;
    unsigned short* __restrict__ OUT = (nb == 0) ? qh : (nb == 1) ? kh : vh;
    const int col0 = (blockIdx.x & 7) * 128;
    const int row0 = blockIdx.y * 64;
    const int lane = tid & 63, wvi = tid >> 6;
    const int wr = (wvi >> 1) * 32, wc = (wvi & 1) * 64;
    const int l15 = lane & 15, quad = lane >> 4;

    const int grow = lane >> 2;            // 0..15
    const int gkc = (lane & 3) * 8;        // element offset within row
    const unsigned short* gA = xb + (size_t)(row0 + wvi * 16 + grow) * 1024 + gkc;
    const unsigned short* gB = Bt + (size_t)(col0 + wvi * 32 + grow) * 1024 + gkc;
    const int lAo = (wvi * 16) * 32;       // wave-uniform offsets in a buffer
    const int lBo = (wvi * 32) * 32;

    f32x4 acc[2][4] = {};
    // prologue: stage tile 0 into buf 0
    gll16(gA, Al[0] + lAo);
    gll16(gB, Bl[0] + lBo);
    gll16(gB + 16 * 1024, Bl[0] + lBo + 16 * 32);
    __syncthreads();                        // buf0 landed (vmcnt0 + barrier)
    for (int it = 0; it < 32; ++it) {
        const int cur = it & 1;
        if (it < 31) {                      // issue next-tile loads first
            const int k1 = (it + 1) * 32;
            gll16(gA + k1, Al[cur ^ 1] + lAo);
            gll16(gB + k1, Bl[cur ^ 1] + lBo);
            gll16(gB + 16 * 1024 + k1, Bl[cur ^ 1] + lBo + 16 * 32);
        }
        bf16x8 af[2], bfr[4];
        #pragma unroll
        for (int i = 0; i < 2; ++i)
            af[i] = *(const bf16x8*)&Al[cur][(wr + i * 16 + l15) * 32 + quad * 8];
        #pragma unroll
        for (int j = 0; j < 4; ++j)
            bfr[j] = *(const bf16x8*)&Bl[cur][(wc + j * 16 + l15) * 32 + quad * 8];
        #pragma unroll
        for (int i = 0; i < 2; ++i)
            #pragma unroll
            for (int j = 0; j < 4; ++j)
                acc[i][j] = __builtin_amdgcn_mfma_f32_16x16x32_bf16(
                    af[i], bfr[j], acc[i][j], 0, 0, 0);
        __syncthreads();   // drains next-tile GLLs (flew under ds_read+MFMA)
    }

    // epilogue: wave's 64 cols = one head; fused RoPE; head-major store
    const int hh = ((blockIdx.x & 7) << 1) + (wc >> 6);
    const bool dorope = (nb != 2);
    #pragma unroll
    for (int i = 0; i < 2; ++i) {
        const int rowb = row0 + wr + i * 16 + quad * 4;
        #pragma unroll
        for (int r = 0; r < 4; ++r) {
            const int s = rowb + r;
            float v0 = acc[i][0][r], v1 = acc[i][1][r];
            float v2 = acc[i][2][r], v3 = acc[i][3][r];
            if (dorope) {
                float c0 = cs[s * 32 + l15],      s0 = sn[s * 32 + l15];
                float c1 = cs[s * 32 + 16 + l15], s1 = sn[s * 32 + 16 + l15];
                float lo0 = v0 * c0 - v2 * s0;
                float hi0 = v2 * c0 + v0 * s0;
                float lo1 = v1 * c1 - v3 * s1;
                float hi1 = v3 * c1 + v1 * s1;
                v0 = lo0; v1 = lo1; v2 = hi0; v3 = hi1;
            }
            unsigned short* op = OUT + (size_t)hh * (S_LEN * 64) + (size_t)s * 64 + l15;
            op[0]  = f2bf(v0);
            op[16] = f2bf(v1);
            op[32] = f2bf(v2);
            op[48] = f2bf(v3);
        }
    }
}

// ---------------------------------------------------------------------------
// Attention (r17-verbatim, restored): one wave per (h,q). Wave-private LDS
// slices; same-address broadcast ds_reads. Phase 4: vectorized V gather —
// lane = (token-quad tq, dim-quad dd); 16 x uint2 loads; addresses from ts
// (phase 1) so loads issue under the softmax chain; 8 shfl_xor cross-tq
// reduce; ushort4 coalesced store from lanes 0..15.
// ---------------------------------------------------------------------------
__global__ __launch_bounds__(256) void attn_kernel(
    const unsigned short* __restrict__ qh, const unsigned short* __restrict__ kh,
    const unsigned short* __restrict__ vh, const int* __restrict__ anc,
    unsigned short* __restrict__ att) {
    __shared__ __align__(16) float qs[4][64];
    __shared__ __align__(16) int   ts[4][64];
    __shared__ __align__(16) float ws[4][64];
    const int w4 = threadIdx.x >> 6;
    const int lane = threadIdx.x & 63;
    const int wid = (blockIdx.x << 2) + w4;
    const int h = wid >> 11;
    const int qi = wid & 2047;
    const size_t hb = (size_t)h * (S_LEN * 64);

    const float q_own = bfu2f(qh[hb + (size_t)qi * 64 + lane]);
    const int slot = lane >> 4;
    const int tile = (slot < 3) ? anc[((size_t)h * S_LEN + qi) * 3 + slot]
                                : (qi >> 4);
    const int tok_own = tile * 16 + (lane & 15);
    qs[w4][lane] = q_own;
    ts[w4][lane] = tok_own;

    const int c = lane & 3;
    const int t = lane >> 2;
    float qv[16];
    #pragma unroll
    for (int r = 0; r < 4; ++r) {
        float4 f = *(const float4*)&qs[w4][c * 16 + r * 4];
        qv[r * 4 + 0] = f.x; qv[r * 4 + 1] = f.y;
        qv[r * 4 + 2] = f.z; qv[r * 4 + 3] = f.w;
    }

    #pragma unroll
    for (int p = 0; p < 4; ++p) {
        const int tk = ts[w4][p * 16 + t];
        const unsigned short* kp = kh + hb + (size_t)tk * 64 + c * 16;
        const uint4 k0 = *(const uint4*)kp;
        const uint4 k1 = *(const uint4*)(kp + 8);
        float part;
        part = bflo(k0.x) * qv[0];
        part = fmaf(bfhi(k0.x), qv[1], part);
        part = fmaf(bflo(k0.y), qv[2], part);
        part = fmaf(bfhi(k0.y), qv[3], part);
        part = fmaf(bflo(k0.z), qv[4], part);
        part = fmaf(bfhi(k0.z), qv[5], part);
        part = fmaf(bflo(k0.w), qv[6], part);
        part = fmaf(bfhi(k0.w), qv[7], part);
        part = fmaf(bflo(k1.x), qv[8], part);
        part = fmaf(bfhi(k1.x), qv[9], part);
        part = fmaf(bflo(k1.y), qv[10], part);
        part = fmaf(bfhi(k1.y), qv[11], part);
        part = fmaf(bflo(k1.z), qv[12], part);
        part = fmaf(bfhi(k1.z), qv[13], part);
        part = fmaf(bflo(k1.w), qv[14], part);
        part = fmaf(bfhi(k1.w), qv[15], part);
        part += __shfl_xor(part, 1, 64);
        part += __shfl_xor(part, 2, 64);
        if (c == 0) ws[w4][p * 16 + t] = part;
    }

    float logit = ws[w4][lane];
    const bool fut = tok_own > qi;
    logit = fut ? -1e30f : logit * 0.125f;

    float m = logit;
    #pragma unroll
    for (int off = 32; off >= 1; off >>= 1)
        m = fmaxf(m, __shfl_xor(m, off, 64));
    const float e = fut ? 0.f : __expf(logit - m);
    float ssum = e;
    #pragma unroll
    for (int off = 32; off >= 1; off >>= 1)
        ssum += __shfl_xor(ssum, off, 64);
    ws[w4][lane] = e / ssum;

    // phase 4: vectorized weighted V sum.
    // lane -> (tq = token quad 0..3, dd = dim quad 0..15); round r covers
    // tokens r*4 .. r*4+3; each lane loads 4 bf16 dims (uint2, 8B).
    const int tq = lane >> 4;
    const int dd = lane & 15;
    const unsigned short* vbase = vh + hb + dd * 4;
    float a0 = 0.f, a1 = 0.f, a2 = 0.f, a3 = 0.f;
    #pragma unroll
    for (int r = 0; r < 16; ++r) {
        const int kk = r * 4 + tq;
        const int tok = ts[w4][kk];
        const uint2 vv = *(const uint2*)(vbase + (size_t)tok * 64);
        const float w = ws[w4][kk];
        a0 = fmaf(w, bflo(vv.x), a0);
        a1 = fmaf(w, bfhi(vv.x), a1);
        a2 = fmaf(w, bflo(vv.y), a2);
        a3 = fmaf(w, bfhi(vv.y), a3);
    }
    a0 += __shfl_xor(a0, 16, 64); a0 += __shfl_xor(a0, 32, 64);
    a1 += __shfl_xor(a1, 16, 64); a1 += __shfl_xor(a1, 32, 64);
    a2 += __shfl_xor(a2, 16, 64); a2 += __shfl_xor(a2, 32, 64);
    a3 += __shfl_xor(a3, 16, 64); a3 += __shfl_xor(a3, 32, 64);
    if (tq == 0) {
        ushort4 o;
        o.x = f2bf(a0); o.y = f2bf(a1); o.z = f2bf(a2); o.w = f2bf(a3);
        *(ushort4*)&att[(size_t)qi * DM + h * HD + dd * 4] = o;
    }
}

// ---------------------------------------------------------------------------
// Out GEMM (r16-verbatim): 64x64 tile, grid (16,32) = 512 blocks = 2/CU.
// Wave tile 32x32; 2 GLL + 4 MFMA per wave per K-iter.
// ---------------------------------------------------------------------------
__global__ __launch_bounds__(256) void gemm_out(
    const unsigned short* __restrict__ A, const unsigned short* __restrict__ Bt,
    float* __restrict__ C) {
    __shared__ __align__(16) unsigned short Al[64 * 32];
    __shared__ __align__(16) unsigned short Bl[64 * 32];
    const int tid = threadIdx.x;
    const int col0 = blockIdx.x * 64;
    const int row0 = blockIdx.y * 64;
    const int lane = tid & 63, wvi = tid >> 6;
    const int wr = (wvi >> 1) * 32, wc = (wvi & 1) * 32;
    const int l15 = lane & 15, quad = lane >> 4;

    const int grow = lane >> 2;
    const int gkc = (lane & 3) * 8;
    const unsigned short* gA = A + (size_t)(row0 + wvi * 16 + grow) * 1024 + gkc;
    const unsigned short* gB = Bt + (size_t)(col0 + wvi * 16 + grow) * 1024 + gkc;
    unsigned short* lA = Al + (wvi * 16) * 32;   // wave-uniform
    unsigned short* lB = Bl + (wvi * 16) * 32;

    f32x4 acc[2][2] = {};
    for (int k0 = 0; k0 < 1024; k0 += 32) {
        __syncthreads();
        gll16(gA + k0, lA);                       // A: 64 rows total
        gll16(gB + k0, lB);                       // B: 64 rows total
        __syncthreads();
        bf16x8 af[2], bfr[2];
        #pragma unroll
        for (int i = 0; i < 2; ++i)
            af[i] = *(const bf16x8*)&Al[(wr + i * 16 + l15) * 32 + quad * 8];
        #pragma unroll
        for (int j = 0; j < 2; ++j)
            bfr[j] = *(const bf16x8*)&Bl[(wc + j * 16 + l15) * 32 + quad * 8];
        #pragma unroll
        for (int i = 0; i < 2; ++i)
            #pragma unroll
            for (int j = 0; j < 2; ++j)
                acc[i][j] = __builtin_amdgcn_mfma_f32_16x16x32_bf16(
                    af[i], bfr[j], acc[i][j], 0, 0, 0);
    }
    #pragma unroll
    for (int i = 0; i < 2; ++i) {
        const int rowb = row0 + wr + i * 16 + quad * 4;
        #pragma unroll
        for (int r = 0; r < 4; ++r) {
            float* crow = C + (size_t)(rowb + r) * 1024 + col0 + wc;
            #pragma unroll
            for (int j = 0; j < 2; ++j)
                crow[j * 16 + l15] = acc[i][j][r];
        }
    }
}

// ---------------------------------------------------------------------------
extern "C" void kernel_launch(void* const* d_in, const int* in_sizes, int n_in,
                              void* d_out, int out_size, void* d_ws, size_t ws_size,
                              hipStream_t stream) {
    const float* x   = (const float*)d_in[0];
    const float* Wq  = (const float*)d_in[1];
    const float* Wk  = (const float*)d_in[2];
    const float* Wv  = (const float*)d_in[3];
    const float* Wo  = (const float*)d_in[4];
    const float* cs  = (const float*)d_in[5];
    const float* sn  = (const float*)d_in[6];
    const int*   anc = (const int*)d_in[7];
    float* out = (float*)d_out;

    unsigned short* xb  = (unsigned short*)d_ws;
    unsigned short* Wtq = xb  + (size_t)2048 * 1024;
    unsigned short* Wtk = Wtq + (size_t)1024 * 1024;
    unsigned short* Wtv = Wtk + (size_t)1024 * 1024;
    unsigned short* Wto = Wtv + (size_t)1024 * 1024;
    unsigned short* qh  = Wto + (size_t)1024 * 1024;   // [H][S][64]
    unsigned short* kh  = qh  + (size_t)2048 * 1024;
    unsigned short* vh  = kh  + (size_t)2048 * 1024;
    unsigned short* att = vh  + (size_t)2048 * 1024;   // [S][H*D]

    prep<<<5120, 256, 0, stream>>>(x, xb, Wq, Wk, Wv, Wo, Wtq, Wtk, Wtv, Wto);
    gemm_qkv<<<dim3(24, 32), 256, 0, stream>>>(xb, Wtq, Wtk, Wtv,
                                               qh, kh, vh, cs, sn);
    attn_kernel<<<(S_LEN * NH) / 4, 256, 0, stream>>>(qh, kh, vh, anc, att);
    gemm_out<<<dim3(16, 32), 256, 0, stream>>>(att, Wto, out);
}

// Round 5
// 149.953 us; speedup vs baseline: 1.2880x; 1.0044x over previous
//
#include <hip/hip_runtime.h>
#include <hip/hip_bf16.h>

// KascadeReuseAttention  B=1, S=2048, DM=1024, H=16, D=64, T=16, NA=3
// Round-21 (base r20 = 150.6us): single change — attn XCD-aware head
// partitioning. Old: h = wid>>11 with round-robin block->XCD dispatch
// puts ALL 16 heads' K/V (8MB) in every XCD's 4MB L2 -> thrash, loads
// served from Infinity Cache at ~2x latency; attn is latency-bound.
// New: bijective remap xcd=bid&7, idx=bid>>3, h=(xcd<<1)|(idx>>9),
// qb=idx&511 -> each XCD touches exactly 2 heads = 512KB K/V, fully
// L2-resident. Pure index change; all phases frozen.
// History: r18 DS-diet regressed (193us: low VGPR killed load hoisting;
// attn lives on ILP). r20 qkv 2-phase dbuf kept (+1.3us).
// Known budget: ~45us harness ws-poison fill (immovable) + ~35 attn +
// ~23 qkv + ~10 prep + out + gaps.

#define S_LEN 2048
#define DM 1024
#define NH 16
#define HD 64

typedef __bf16 bf16x8 __attribute__((ext_vector_type(8)));
typedef float f32x4 __attribute__((ext_vector_type(4)));

static __device__ __forceinline__ unsigned short f2bf(float f) {
    union { float f; unsigned int i; } un;
    un.f = f;
    unsigned int r = un.i + 0x7FFFu + ((un.i >> 16) & 1u);  // RNE
    return (unsigned short)(r >> 16);
}
static __device__ __forceinline__ float bfu2f(unsigned short u) {
    union { unsigned int i; float f; } un;
    un.i = ((unsigned int)u) << 16;
    return un.f;
}
static __device__ __forceinline__ float bflo(unsigned int u) {
    union { unsigned int i; float f; } un;
    un.i = u << 16;
    return un.f;
}
static __device__ __forceinline__ float bfhi(unsigned int u) {
    union { unsigned int i; float f; } un;
    un.i = u & 0xFFFF0000u;
    return un.f;
}

// async global->LDS, 16 B per lane; LDS dest = uniform base + lane*16.
static __device__ __forceinline__ void gll16(const unsigned short* g,
                                             unsigned short* l) {
    __builtin_amdgcn_global_load_lds(
        (const __attribute__((address_space(1))) unsigned int*)(uintptr_t)g,
        (__attribute__((address_space(3))) unsigned int*)(uintptr_t)l,
        16, 0, 0);
}

// ---------------------------------------------------------------------------
// prep: blocks [0,4096) transpose W* fp32->bf16 [n][k]; blocks [4096,5120)
// convert x fp32->bf16.
// ---------------------------------------------------------------------------
__global__ __launch_bounds__(256) void prep(
    const float* __restrict__ x, unsigned short* __restrict__ xb,
    const float* __restrict__ W0, const float* __restrict__ W1,
    const float* __restrict__ W2, const float* __restrict__ W3,
    unsigned short* __restrict__ T0, unsigned short* __restrict__ T1,
    unsigned short* __restrict__ T2, unsigned short* __restrict__ T3) {
    const int bx = blockIdx.x;
    if (bx < 4096) {
        const int z = bx >> 10, rem = bx & 1023;
        const float* W = (z == 0) ? W0 : (z == 1) ? W1 : (z == 2) ? W2 : W3;
        unsigned short* T = (z == 0) ? T0 : (z == 1) ? T1 : (z == 2) ? T2 : T3;
        __shared__ float t[32][33];
        const int bn = (rem & 31) * 32, bk = (rem >> 5) * 32;
        const int tx = threadIdx.x & 31, ty = threadIdx.x >> 5;
        #pragma unroll
        for (int m = 0; m < 4; ++m)
            t[ty + m * 8][tx] = W[(size_t)(bk + ty + m * 8) * 1024 + bn + tx];
        __syncthreads();
        #pragma unroll
        for (int m = 0; m < 4; ++m)
            T[(size_t)(bn + ty + m * 8) * 1024 + bk + tx] = f2bf(t[tx][ty + m * 8]);
    } else {
        const int i = (bx - 4096) * 2048 + threadIdx.x * 8;
        float4 f0 = *(const float4*)(x + i);
        float4 f1 = *(const float4*)(x + i + 4);
        ushort4 o0, o1;
        o0.x = f2bf(f0.x); o0.y = f2bf(f0.y); o0.z = f2bf(f0.z); o0.w = f2bf(f0.w);
        o1.x = f2bf(f1.x); o1.y = f2bf(f1.y); o1.z = f2bf(f1.z); o1.w = f2bf(f1.w);
        *(ushort4*)(xb + i) = o0;
        *(ushort4*)(xb + i + 4) = o1;
    }
}

// ---------------------------------------------------------------------------
// QKV GEMM (r20-verbatim): 64x128 tile, BK=32, grid (24,32) = 768 blocks
// (3/CU), GLL width-16 staging, 2-phase double-buffered: stage tile t+1
// into buf^1 before computing tile t; one barrier per K-step.
// Fused RoPE epilogue, head-major bf16 out [H][S][64].
// ---------------------------------------------------------------------------
__global__ __launch_bounds__(256) void gemm_qkv(
    const unsigned short* __restrict__ xb,
    const unsigned short* __restrict__ Wtq, const unsigned short* __restrict__ Wtk,
    const unsigned short* __restrict__ Wtv,
    unsigned short* __restrict__ qh, unsigned short* __restrict__ kh,
    unsigned short* __restrict__ vh,
    const float* __restrict__ cs, const float* __restrict__ sn) {
    __shared__ __align__(16) unsigned short Al[2][64 * 32];
    __shared__ __align__(16) unsigned short Bl[2][128 * 32];
    const int tid = threadIdx.x;
    const int nb = blockIdx.x >> 3;
    const unsigned short* __restrict__ Bt = (nb == 0) ? Wtq : (nb == 1) ? Wtk : Wtv;
    unsigned short* __restrict__ OUT = (nb == 0) ? qh : (nb == 1) ? kh : vh;
    const int col0 = (blockIdx.x & 7) * 128;
    const int row0 = blockIdx.y * 64;
    const int lane = tid & 63, wvi = tid >> 6;
    const int wr = (wvi >> 1) * 32, wc = (wvi & 1) * 64;
    const int l15 = lane & 15, quad = lane >> 4;

    const int grow = lane >> 2;            // 0..15
    const int gkc = (lane & 3) * 8;        // element offset within row
    const unsigned short* gA = xb + (size_t)(row0 + wvi * 16 + grow) * 1024 + gkc;
    const unsigned short* gB = Bt + (size_t)(col0 + wvi * 32 + grow) * 1024 + gkc;
    const int lAo = (wvi * 16) * 32;       // wave-uniform offsets in a buffer
    const int lBo = (wvi * 32) * 32;

    f32x4 acc[2][4] = {};
    // prologue: stage tile 0 into buf 0
    gll16(gA, Al[0] + lAo);
    gll16(gB, Bl[0] + lBo);
    gll16(gB + 16 * 1024, Bl[0] + lBo + 16 * 32);
    __syncthreads();                        // buf0 landed (vmcnt0 + barrier)
    for (int it = 0; it < 32; ++it) {
        const int cur = it & 1;
        if (it < 31) {                      // issue next-tile loads first
            const int k1 = (it + 1) * 32;
            gll16(gA + k1, Al[cur ^ 1] + lAo);
            gll16(gB + k1, Bl[cur ^ 1] + lBo);
            gll16(gB + 16 * 1024 + k1, Bl[cur ^ 1] + lBo + 16 * 32);
        }
        bf16x8 af[2], bfr[4];
        #pragma unroll
        for (int i = 0; i < 2; ++i)
            af[i] = *(const bf16x8*)&Al[cur][(wr + i * 16 + l15) * 32 + quad * 8];
        #pragma unroll
        for (int j = 0; j < 4; ++j)
            bfr[j] = *(const bf16x8*)&Bl[cur][(wc + j * 16 + l15) * 32 + quad * 8];
        #pragma unroll
        for (int i = 0; i < 2; ++i)
            #pragma unroll
            for (int j = 0; j < 4; ++j)
                acc[i][j] = __builtin_amdgcn_mfma_f32_16x16x32_bf16(
                    af[i], bfr[j], acc[i][j], 0, 0, 0);
        __syncthreads();   // drains next-tile GLLs (flew under ds_read+MFMA)
    }

    // epilogue: wave's 64 cols = one head; fused RoPE; head-major store
    const int hh = ((blockIdx.x & 7) << 1) + (wc >> 6);
    const bool dorope = (nb != 2);
    #pragma unroll
    for (int i = 0; i < 2; ++i) {
        const int rowb = row0 + wr + i * 16 + quad * 4;
        #pragma unroll
        for (int r = 0; r < 4; ++r) {
            const int s = rowb + r;
            float v0 = acc[i][0][r], v1 = acc[i][1][r];
            float v2 = acc[i][2][r], v3 = acc[i][3][r];
            if (dorope) {
                float c0 = cs[s * 32 + l15],      s0 = sn[s * 32 + l15];
                float c1 = cs[s * 32 + 16 + l15], s1 = sn[s * 32 + 16 + l15];
                float lo0 = v0 * c0 - v2 * s0;
                float hi0 = v2 * c0 + v0 * s0;
                float lo1 = v1 * c1 - v3 * s1;
                float hi1 = v3 * c1 + v1 * s1;
                v0 = lo0; v1 = lo1; v2 = hi0; v3 = hi1;
            }
            unsigned short* op = OUT + (size_t)hh * (S_LEN * 64) + (size_t)s * 64 + l15;
            op[0]  = f2bf(v0);
            op[16] = f2bf(v1);
            op[32] = f2bf(v2);
            op[48] = f2bf(v3);
        }
    }
}

// ---------------------------------------------------------------------------
// Attention (r21): r17 phases verbatim; ONLY the block->(h,q) mapping is
// changed to be XCD-aware: xcd=bid&7 owns heads {2*xcd, 2*xcd+1}, so each
// XCD's L2 serves a 512KB K/V working set instead of 8MB.
// ---------------------------------------------------------------------------
__global__ __launch_bounds__(256) void attn_kernel(
    const unsigned short* __restrict__ qh, const unsigned short* __restrict__ kh,
    const unsigned short* __restrict__ vh, const int* __restrict__ anc,
    unsigned short* __restrict__ att) {
    __shared__ __align__(16) float qs[4][64];
    __shared__ __align__(16) int   ts[4][64];
    __shared__ __align__(16) float ws[4][64];
    const int w4 = threadIdx.x >> 6;
    const int lane = threadIdx.x & 63;
    // XCD-aware remap (bijective over 8192 blocks): round-robin dispatch
    // puts bid%8 on XCD (bid&7); give each XCD 2 whole heads.
    const int bid = blockIdx.x;
    const int xcd = bid & 7;
    const int idx = bid >> 3;                  // 0..1023
    const int h   = (xcd << 1) | (idx >> 9);   // 2 heads per XCD
    const int qi  = ((idx & 511) << 2) + w4;   // 512 q-blocks per head
    const size_t hb = (size_t)h * (S_LEN * 64);

    const float q_own = bfu2f(qh[hb + (size_t)qi * 64 + lane]);
    const int slot = lane >> 4;
    const int tile = (slot < 3) ? anc[((size_t)h * S_LEN + qi) * 3 + slot]
                                : (qi >> 4);
    const int tok_own = tile * 16 + (lane & 15);
    qs[w4][lane] = q_own;
    ts[w4][lane] = tok_own;

    const int c = lane & 3;
    const int t = lane >> 2;
    float qv[16];
    #pragma unroll
    for (int r = 0; r < 4; ++r) {
        float4 f = *(const float4*)&qs[w4][c * 16 + r * 4];
        qv[r * 4 + 0] = f.x; qv[r * 4 + 1] = f.y;
        qv[r * 4 + 2] = f.z; qv[r * 4 + 3] = f.w;
    }

    #pragma unroll
    for (int p = 0; p < 4; ++p) {
        const int tk = ts[w4][p * 16 + t];
        const unsigned short* kp = kh + hb + (size_t)tk * 64 + c * 16;
        const uint4 k0 = *(const uint4*)kp;
        const uint4 k1 = *(const uint4*)(kp + 8);
        float part;
        part = bflo(k0.x) * qv[0];
        part = fmaf(bfhi(k0.x), qv[1], part);
        part = fmaf(bflo(k0.y), qv[2], part);
        part = fmaf(bfhi(k0.y), qv[3], part);
        part = fmaf(bflo(k0.z), qv[4], part);
        part = fmaf(bfhi(k0.z), qv[5], part);
        part = fmaf(bflo(k0.w), qv[6], part);
        part = fmaf(bfhi(k0.w), qv[7], part);
        part = fmaf(bflo(k1.x), qv[8], part);
        part = fmaf(bfhi(k1.x), qv[9], part);
        part = fmaf(bflo(k1.y), qv[10], part);
        part = fmaf(bfhi(k1.y), qv[11], part);
        part = fmaf(bflo(k1.z), qv[12], part);
        part = fmaf(bfhi(k1.z), qv[13], part);
        part = fmaf(bflo(k1.w), qv[14], part);
        part = fmaf(bfhi(k1.w), qv[15], part);
        part += __shfl_xor(part, 1, 64);
        part += __shfl_xor(part, 2, 64);
        if (c == 0) ws[w4][p * 16 + t] = part;
    }

    float logit = ws[w4][lane];
    const bool fut = tok_own > qi;
    logit = fut ? -1e30f : logit * 0.125f;

    float m = logit;
    #pragma unroll
    for (int off = 32; off >= 1; off >>= 1)
        m = fmaxf(m, __shfl_xor(m, off, 64));
    const float e = fut ? 0.f : __expf(logit - m);
    float ssum = e;
    #pragma unroll
    for (int off = 32; off >= 1; off >>= 1)
        ssum += __shfl_xor(ssum, off, 64);
    ws[w4][lane] = e / ssum;

    // phase 4: vectorized weighted V sum.
    // lane -> (tq = token quad 0..3, dd = dim quad 0..15); round r covers
    // tokens r*4 .. r*4+3; each lane loads 4 bf16 dims (uint2, 8B).
    const int tq = lane >> 4;
    const int dd = lane & 15;
    const unsigned short* vbase = vh + hb + dd * 4;
    float a0 = 0.f, a1 = 0.f, a2 = 0.f, a3 = 0.f;
    #pragma unroll
    for (int r = 0; r < 16; ++r) {
        const int kk = r * 4 + tq;
        const int tok = ts[w4][kk];
        const uint2 vv = *(const uint2*)(vbase + (size_t)tok * 64);
        const float w = ws[w4][kk];
        a0 = fmaf(w, bflo(vv.x), a0);
        a1 = fmaf(w, bfhi(vv.x), a1);
        a2 = fmaf(w, bflo(vv.y), a2);
        a3 = fmaf(w, bfhi(vv.y), a3);
    }
    a0 += __shfl_xor(a0, 16, 64); a0 += __shfl_xor(a0, 32, 64);
    a1 += __shfl_xor(a1, 16, 64); a1 += __shfl_xor(a1, 32, 64);
    a2 += __shfl_xor(a2, 16, 64); a2 += __shfl_xor(a2, 32, 64);
    a3 += __shfl_xor(a3, 16, 64); a3 += __shfl_xor(a3, 32, 64);
    if (tq == 0) {
        ushort4 o;
        o.x = f2bf(a0); o.y = f2bf(a1); o.z = f2bf(a2); o.w = f2bf(a3);
        *(ushort4*)&att[(size_t)qi * DM + h * HD + dd * 4] = o;
    }
}

// ---------------------------------------------------------------------------
// Out GEMM (r16-verbatim): 64x64 tile, grid (16,32) = 512 blocks = 2/CU.
// Wave tile 32x32; 2 GLL + 4 MFMA per wave per K-iter.
// ---------------------------------------------------------------------------
__global__ __launch_bounds__(256) void gemm_out(
    const unsigned short* __restrict__ A, const unsigned short* __restrict__ Bt,
    float* __restrict__ C) {
    __shared__ __align__(16) unsigned short Al[64 * 32];
    __shared__ __align__(16) unsigned short Bl[64 * 32];
    const int tid = threadIdx.x;
    const int col0 = blockIdx.x * 64;
    const int row0 = blockIdx.y * 64;
    const int lane = tid & 63, wvi = tid >> 6;
    const int wr = (wvi >> 1) * 32, wc = (wvi & 1) * 32;
    const int l15 = lane & 15, quad = lane >> 4;

    const int grow = lane >> 2;
    const int gkc = (lane & 3) * 8;
    const unsigned short* gA = A + (size_t)(row0 + wvi * 16 + grow) * 1024 + gkc;
    const unsigned short* gB = Bt + (size_t)(col0 + wvi * 16 + grow) * 1024 + gkc;
    unsigned short* lA = Al + (wvi * 16) * 32;   // wave-uniform
    unsigned short* lB = Bl + (wvi * 16) * 32;

    f32x4 acc[2][2] = {};
    for (int k0 = 0; k0 < 1024; k0 += 32) {
        __syncthreads();
        gll16(gA + k0, lA);                       // A: 64 rows total
        gll16(gB + k0, lB);                       // B: 64 rows total
        __syncthreads();
        bf16x8 af[2], bfr[2];
        #pragma unroll
        for (int i = 0; i < 2; ++i)
            af[i] = *(const bf16x8*)&Al[(wr + i * 16 + l15) * 32 + quad * 8];
        #pragma unroll
        for (int j = 0; j < 2; ++j)
            bfr[j] = *(const bf16x8*)&Bl[(wc + j * 16 + l15) * 32 + quad * 8];
        #pragma unroll
        for (int i = 0; i < 2; ++i)
            #pragma unroll
            for (int j = 0; j < 2; ++j)
                acc[i][j] = __builtin_amdgcn_mfma_f32_16x16x32_bf16(
                    af[i], bfr[j], acc[i][j], 0, 0, 0);
    }
    #pragma unroll
    for (int i = 0; i < 2; ++i) {
        const int rowb = row0 + wr + i * 16 + quad * 4;
        #pragma unroll
        for (int r = 0; r < 4; ++r) {
            float* crow = C + (size_t)(rowb + r) * 1024 + col0 + wc;
            #pragma unroll
            for (int j = 0; j < 2; ++j)
                crow[j * 16 + l15] = acc[i][j][r];
        }
    }
}

// ---------------------------------------------------------------------------
extern "C" void kernel_launch(void* const* d_in, const int* in_sizes, int n_in,
                              void* d_out, int out_size, void* d_ws, size_t ws_size,
                              hipStream_t stream) {
    const float* x   = (const float*)d_in[0];
    const float* Wq  = (const float*)d_in[1];
    const float* Wk  = (const float*)d_in[2];
    const float* Wv  = (const float*)d_in[3];
    const float* Wo  = (const float*)d_in[4];
    const float* cs  = (const float*)d_in[5];
    const float* sn  = (const float*)d_in[6];
    const int*   anc = (const int*)d_in[7];
    float* out = (float*)d_out;

    unsigned short* xb  = (unsigned short*)d_ws;
    unsigned short* Wtq = xb  + (size_t)2048 * 1024;
    unsigned short* Wtk = Wtq + (size_t)1024 * 1024;
    unsigned short* Wtv = Wtk + (size_t)1024 * 1024;
    unsigned short* Wto = Wtv + (size_t)1024 * 1024;
    unsigned short* qh  = Wto + (size_t)1024 * 1024;   // [H][S][64]
    unsigned short* kh  = qh  + (size_t)2048 * 1024;
    unsigned short* vh  = kh  + (size_t)2048 * 1024;
    unsigned short* att = vh  + (size_t)2048 * 1024;   // [S][H*D]

    prep<<<5120, 256, 0, stream>>>(x, xb, Wq, Wk, Wv, Wo, Wtq, Wtk, Wtv, Wto);
    gemm_qkv<<<dim3(24, 32), 256, 0, stream>>>(xb, Wtq, Wtk, Wtv,
                                               qh, kh, vh, cs, sn);
    attn_kernel<<<(S_LEN * NH) / 4, 256, 0, stream>>>(qh, kh, vh, anc, att);
    gemm_out<<<dim3(16, 32), 256, 0, stream>>>(att, Wto, out);
}